// Round 3
// baseline (517.360 us; speedup 1.0000x reference)
//
#include <hip/hip_runtime.h>

#define NN 50000
#define NE 800000
#define FIN 128
#define HD 64
#define SL 3
#define NBL 196  // ceil(NN/256)

// ---------------- bf16 pack helpers (RNE) ----------------

__device__ __forceinline__ unsigned int bfr(float x) {
    unsigned int u = __float_as_uint(x);
    return (u + 0x7fffu + ((u >> 16) & 1u)) >> 16;
}
__device__ __forceinline__ unsigned int bf2(float lo, float hi) {
    return bfr(lo) | (bfr(hi) << 16);
}

// ---------------- CSR build ----------------

__global__ void hist_k(const int* __restrict__ dst, int* __restrict__ cnt) {
    int e = blockIdx.x * blockDim.x + threadIdx.x;
    if (e < NE) atomicAdd(&cnt[dst[e]], 1);
}

__global__ __launch_bounds__(256) void partial_k(const int* __restrict__ cnt,
                                                 int* __restrict__ partials) {
    __shared__ int sh[256];
    int t = threadIdx.x;
    int idx = blockIdx.x * 256 + t;
    sh[t] = (idx < NN) ? cnt[idx] : 0;
    __syncthreads();
    for (int d = 128; d > 0; d >>= 1) {
        if (t < d) sh[t] += sh[t + d];
        __syncthreads();
    }
    if (t == 0) partials[blockIdx.x] = sh[0];
}

__global__ __launch_bounds__(256) void scanp_k(const int* __restrict__ partials,
                                               int* __restrict__ pscan,
                                               int* __restrict__ off) {
    __shared__ int sh[256];
    int t = threadIdx.x;
    int v = (t < NBL) ? partials[t] : 0;
    sh[t] = v;
    __syncthreads();
    for (int d = 1; d < 256; d <<= 1) {
        int u = (t >= d) ? sh[t - d] : 0;
        __syncthreads();
        sh[t] += u;
        __syncthreads();
    }
    if (t < NBL) pscan[t] = sh[t] - v;  // exclusive
    if (t == 255) off[NN] = sh[255];    // total = NE
}

__global__ __launch_bounds__(256) void offs_k(const int* __restrict__ cnt,
                                              const int* __restrict__ pscan,
                                              int* __restrict__ off,
                                              int* __restrict__ cur) {
    __shared__ int sh[256];
    int t = threadIdx.x;
    int idx = blockIdx.x * 256 + t;
    int v = (idx < NN) ? cnt[idx] : 0;
    sh[t] = v;
    __syncthreads();
    for (int d = 1; d < 256; d <<= 1) {
        int u = (t >= d) ? sh[t - d] : 0;
        __syncthreads();
        sh[t] += u;
        __syncthreads();
    }
    if (idx < NN) {
        int o = pscan[blockIdx.x] + sh[t] - v;  // exclusive
        off[idx] = o;
        cur[idx] = o;
    }
}

// packed (src, attr) single 8B scattered write — halves dirty-line traffic vs 2x4B
__global__ void fill_k(const int* __restrict__ src, const int* __restrict__ dst,
                       const float* __restrict__ attr, int* __restrict__ cur,
                       int2* __restrict__ cedge) {
    int e = blockIdx.x * blockDim.x + threadIdx.x;
    if (e < NE) {
        int d = dst[e];
        int p = atomicAdd(&cur[d], 1);
        cedge[p] = make_int2(src[e], __float_as_int(attr[e]));
    }
}

// ---------------- scatter: m[n] = sum_{e: dst=n} attr[e] * hb[src[e]] ----------------
// wave per dst node, 2 edges per wave iteration (half-wave per edge),
// bf16 gather (128B/edge), fp32 accumulate, shfl_xor(32) merge, no atomics.

__global__ __launch_bounds__(256) void scatter_k(const unsigned int* __restrict__ hb32,
                                                 const int* __restrict__ off,
                                                 const int2* __restrict__ cedge,
                                                 float* __restrict__ m) {
    int w    = (blockIdx.x * blockDim.x + threadIdx.x) >> 6;
    int lane = threadIdx.x & 63;
    if (w >= NN) return;
    int half = lane >> 5;   // which edge of the pair
    int u    = lane & 31;   // uint index within row (features 2u, 2u+1)
    int s = off[w], e = off[w + 1];
    float acc0 = 0.f, acc1 = 0.f;
    int i = s;
    for (; i + 4 <= e; i += 4) {
        int2 eA = cedge[i + half];
        int2 eB = cedge[i + 2 + half];
        unsigned int hA = hb32[(size_t)eA.x * 32 + u];
        unsigned int hB = hb32[(size_t)eB.x * 32 + u];
        float aA = __int_as_float(eA.y);
        float aB = __int_as_float(eB.y);
        acc0 += aA * __uint_as_float(hA << 16);
        acc1 += aA * __uint_as_float(hA & 0xffff0000u);
        acc0 += aB * __uint_as_float(hB << 16);
        acc1 += aB * __uint_as_float(hB & 0xffff0000u);
    }
    for (; i + 2 <= e; i += 2) {
        int2 ed = cedge[i + half];
        unsigned int hv = hb32[(size_t)ed.x * 32 + u];
        float a = __int_as_float(ed.y);
        acc0 += a * __uint_as_float(hv << 16);
        acc1 += a * __uint_as_float(hv & 0xffff0000u);
    }
    if (i < e && half == 0) {  // odd tail: half 0 only
        int2 ed = cedge[i];
        unsigned int hv = hb32[(size_t)ed.x * 32 + u];
        float a = __int_as_float(ed.y);
        acc0 += a * __uint_as_float(hv << 16);
        acc1 += a * __uint_as_float(hv & 0xffff0000u);
    }
    acc0 += __shfl_xor(acc0, 32);
    acc1 += __shfl_xor(acc1, 32);
    if (half == 0)
        ((float2*)m)[(size_t)w * 32 + u] = make_float2(acc0, acc1);
}

// ---------------- conv GEMM stage: out = [hprev +] relu(m@W1+b1)@W2+b2 ----------------

__device__ __forceinline__ float f4get(const float4 v, int k) {
    return k == 0 ? v.x : k == 1 ? v.y : k == 2 ? v.z : v.w;
}

template <bool ADD, bool WB>
__global__ __launch_bounds__(256) void conv_k(const float* __restrict__ m,
                                              const float* __restrict__ W1,
                                              const float* __restrict__ b1,
                                              const float* __restrict__ W2,
                                              const float* __restrict__ b2,
                                              const float* __restrict__ hprev,
                                              float* __restrict__ out,
                                              unsigned int* __restrict__ hbout) {
    __shared__ float4 W1s[1024];  // 64x64
    __shared__ float4 W2s[1024];
    __shared__ float4 b1s[16];
    __shared__ float4 b2s[16];
    const float4* W1g = (const float4*)W1;
    const float4* W2g = (const float4*)W2;
    for (int idx = threadIdx.x; idx < 1024; idx += 256) {
        W1s[idx] = W1g[idx];
        W2s[idx] = W2g[idx];
    }
    if (threadIdx.x < 16)      b1s[threadIdx.x]      = ((const float4*)b1)[threadIdx.x];
    else if (threadIdx.x < 32) b2s[threadIdx.x - 16] = ((const float4*)b2)[threadIdx.x - 16];
    __syncthreads();

    int r = blockIdx.x * blockDim.x + threadIdx.x;
    if (r >= NN) return;
    const float4* mp = (const float4*)(m + (size_t)r * HD);

    float4 t4[16];
#pragma unroll
    for (int j = 0; j < 16; j++) t4[j] = b1s[j];
    for (int k4 = 0; k4 < 16; k4++) {
        float4 mv = mp[k4];
#pragma unroll
        for (int kk = 0; kk < 4; kk++) {
            float mk = f4get(mv, kk);
            const float4* wrow = &W1s[(k4 * 4 + kk) * 16];
#pragma unroll
            for (int j = 0; j < 16; j++) {
                float4 w = wrow[j];
                t4[j].x += mk * w.x; t4[j].y += mk * w.y;
                t4[j].z += mk * w.z; t4[j].w += mk * w.w;
            }
        }
    }
#pragma unroll
    for (int j = 0; j < 16; j++) {
        t4[j].x = fmaxf(t4[j].x, 0.f); t4[j].y = fmaxf(t4[j].y, 0.f);
        t4[j].z = fmaxf(t4[j].z, 0.f); t4[j].w = fmaxf(t4[j].w, 0.f);
    }

    float4 o4[16];
#pragma unroll
    for (int j = 0; j < 16; j++) o4[j] = b2s[j];
#pragma unroll
    for (int k4 = 0; k4 < 16; k4++) {
#pragma unroll
        for (int kk = 0; kk < 4; kk++) {
            float tk = f4get(t4[k4], kk);
            const float4* wrow = &W2s[(k4 * 4 + kk) * 16];
#pragma unroll
            for (int j = 0; j < 16; j++) {
                float4 w = wrow[j];
                o4[j].x += tk * w.x; o4[j].y += tk * w.y;
                o4[j].z += tk * w.z; o4[j].w += tk * w.w;
            }
        }
    }

    if constexpr (ADD) {
        const float4* hp = (const float4*)(hprev + (size_t)r * HD);
#pragma unroll
        for (int j = 0; j < 16; j++) {
            float4 hv = hp[j];
            o4[j].x += hv.x; o4[j].y += hv.y; o4[j].z += hv.z; o4[j].w += hv.w;
        }
    }
    float4* op = (float4*)(out + (size_t)r * HD);
#pragma unroll
    for (int j = 0; j < 16; j++) op[j] = o4[j];

    if constexpr (WB) {  // fused bf16 copy for next scatter's gather
        uint2* hbp = (uint2*)(hbout + (size_t)r * 32);
#pragma unroll
        for (int j = 0; j < 16; j++) {
            uint2 p;
            p.x = bf2(o4[j].x, o4[j].y);
            p.y = bf2(o4[j].z, o4[j].w);
            hbp[j] = p;
        }
    }
}

// ---------------- input linear: h0 = x @ lin_W + lin_b (+ bf16 copy) ----------------

__global__ __launch_bounds__(256) void lin_k(const float* __restrict__ x,
                                             const float* __restrict__ W,
                                             const float* __restrict__ b,
                                             float* __restrict__ h0,
                                             unsigned int* __restrict__ hb) {
    __shared__ float4 Ws[2048];  // 128x64
    __shared__ float4 bs[16];
    const float4* Wg = (const float4*)W;
    for (int idx = threadIdx.x; idx < 2048; idx += 256) Ws[idx] = Wg[idx];
    if (threadIdx.x < 16) bs[threadIdx.x] = ((const float4*)b)[threadIdx.x];
    __syncthreads();

    int r = blockIdx.x * blockDim.x + threadIdx.x;
    if (r >= NN) return;
    const float4* xp = (const float4*)(x + (size_t)r * FIN);

    float4 t4[16];
#pragma unroll
    for (int j = 0; j < 16; j++) t4[j] = bs[j];
    for (int k4 = 0; k4 < 32; k4++) {
        float4 xv = xp[k4];
#pragma unroll
        for (int kk = 0; kk < 4; kk++) {
            float xk = f4get(xv, kk);
            const float4* wrow = &Ws[(k4 * 4 + kk) * 16];
#pragma unroll
            for (int j = 0; j < 16; j++) {
                float4 w = wrow[j];
                t4[j].x += xk * w.x; t4[j].y += xk * w.y;
                t4[j].z += xk * w.z; t4[j].w += xk * w.w;
            }
        }
    }
    float4* hp = (float4*)(h0 + (size_t)r * HD);
    uint2*  hbp = (uint2*)(hb + (size_t)r * 32);
#pragma unroll
    for (int j = 0; j < 16; j++) {
        hp[j] = t4[j];
        uint2 p;
        p.x = bf2(t4[j].x, t4[j].y);
        p.y = bf2(t4[j].z, t4[j].w);
        hbp[j] = p;
    }
}

// ---------------- launch ----------------

extern "C" void kernel_launch(void* const* d_in, const int* in_sizes, int n_in,
                              void* d_out, int out_size, void* d_ws, size_t ws_size,
                              hipStream_t stream) {
    (void)in_sizes; (void)n_in; (void)out_size; (void)ws_size;

    const float* x    = (const float*)d_in[0];
    const int*   ei   = (const int*)d_in[1];
    const float* attr = (const float*)d_in[2];
    const float* linW = (const float*)d_in[3];
    const float* linb = (const float*)d_in[4];
    const float* W1   = (const float*)d_in[5];
    const float* b1   = (const float*)d_in[6];
    const float* W2   = (const float*)d_in[7];
    const float* b2   = (const float*)d_in[8];
    float* out = (float*)d_out;

    // workspace layout (8B alignment maintained at each boundary)
    float*        h0    = (float*)d_ws;                          // NN*HD f32   (12.8MB)
    float*        m     = h0 + (size_t)NN * HD;                  // NN*HD f32   (12.8MB)
    unsigned int* hb    = (unsigned int*)(m + (size_t)NN * HD);  // NN*32 u32   (6.4MB)
    int2*         cedge = (int2*)(hb + (size_t)NN * 32);         // NE int2     (6.4MB)
    int*          cnt   = (int*)(cedge + NE);                    // NN
    int*          off   = cnt + NN;                              // NN+1
    int*          cur   = off + NN + 1;                          // NN
    int*          parts = cur + NN;                              // 256
    int*          pscan = parts + 256;                           // 256

    const int* src = ei;
    const int* dst = ei + NE;

    float* scats = out;
    float* outs  = out + (size_t)SL * NN * HD;

    const size_t NH = (size_t)NN * HD;
    const int EB = (NE + 255) / 256;   // 3125
    const int GB = (NN + 255) / 256;   // 196
    const int WB = (NN * 64) / 256;    // 12500 (wave per node)

    // CSR build
    hipMemsetAsync(cnt, 0, NN * sizeof(int), stream);
    hist_k<<<EB, 256, 0, stream>>>(dst, cnt);
    partial_k<<<NBL, 256, 0, stream>>>(cnt, parts);
    scanp_k<<<1, 256, 0, stream>>>(parts, pscan, off);
    offs_k<<<NBL, 256, 0, stream>>>(cnt, pscan, off, cur);
    fill_k<<<EB, 256, 0, stream>>>(src, dst, attr, cur, cedge);

    // h0 = x @ lin_W + lin_b (+ bf16 copy into hb)
    lin_k<<<GB, 256, 0, stream>>>(x, linW, linb, h0, hb);

    // layer 0
    scatter_k<<<WB, 256, 0, stream>>>(hb, off, cedge, m);
    conv_k<true, true><<<GB, 256, 0, stream>>>(m, W1, b1, W2, b2, h0, outs, hb);

    // scatter(outs0) reused for scats0 (W0) and layer-1 conv (W1)
    scatter_k<<<WB, 256, 0, stream>>>(hb, off, cedge, m);
    conv_k<false, false><<<GB, 256, 0, stream>>>(m, W1, b1, W2, b2, nullptr, scats, nullptr);
    conv_k<true, true><<<GB, 256, 0, stream>>>(m, W1 + 4096, b1 + 64, W2 + 4096, b2 + 64,
                                               outs, outs + NH, hb);

    // scatter(outs1) reused for scats1 (W1) and layer-2 conv (W2)
    scatter_k<<<WB, 256, 0, stream>>>(hb, off, cedge, m);
    conv_k<false, false><<<GB, 256, 0, stream>>>(m, W1 + 4096, b1 + 64, W2 + 4096, b2 + 64,
                                                 nullptr, scats + NH, nullptr);
    conv_k<true, true><<<GB, 256, 0, stream>>>(m, W1 + 8192, b1 + 128, W2 + 8192, b2 + 128,
                                               outs + NH, outs + 2 * NH, hb);

    // scatter(outs2) for scats2 (W2)
    scatter_k<<<WB, 256, 0, stream>>>(hb, off, cedge, m);
    conv_k<false, false><<<GB, 256, 0, stream>>>(m, W1 + 8192, b1 + 128, W2 + 8192, b2 + 128,
                                                 nullptr, scats + 2 * NH, nullptr);
}

// Round 4
// 307.843 us; speedup vs baseline: 1.6806x; 1.6806x over previous
//
#include <hip/hip_runtime.h>

#define NN 50000
#define NE 800000
#define FIN 128
#define HD 64
#define SL 3
#define NBL 196   // ceil(NN/256)
#define GBM 782   // ceil(NN/64) row-tiles for MFMA kernels

typedef __attribute__((ext_vector_type(8))) short bf16x8;
typedef __attribute__((ext_vector_type(4))) float f32x4;
#define MFMA(A, B, C) __builtin_amdgcn_mfma_f32_16x16x32_bf16(A, B, C, 0, 0, 0)

// ---------------- bf16 pack helpers (RNE) ----------------

__device__ __forceinline__ unsigned int bfr(float x) {
    unsigned int u = __float_as_uint(x);
    return (u + 0x7fffu + ((u >> 16) & 1u)) >> 16;
}
__device__ __forceinline__ unsigned int bf2(float lo, float hi) {
    return bfr(lo) | (bfr(hi) << 16);
}

// ---------------- CSR build ----------------

__global__ void hist_k(const int* __restrict__ dst, int* __restrict__ cnt) {
    int e = blockIdx.x * blockDim.x + threadIdx.x;
    if (e < NE) atomicAdd(&cnt[dst[e]], 1);
}

__global__ __launch_bounds__(256) void partial_k(const int* __restrict__ cnt,
                                                 int* __restrict__ partials) {
    __shared__ int sh[256];
    int t = threadIdx.x;
    int idx = blockIdx.x * 256 + t;
    sh[t] = (idx < NN) ? cnt[idx] : 0;
    __syncthreads();
    for (int d = 128; d > 0; d >>= 1) {
        if (t < d) sh[t] += sh[t + d];
        __syncthreads();
    }
    if (t == 0) partials[blockIdx.x] = sh[0];
}

__global__ __launch_bounds__(256) void scanp_k(const int* __restrict__ partials,
                                               int* __restrict__ pscan,
                                               int* __restrict__ off) {
    __shared__ int sh[256];
    int t = threadIdx.x;
    int v = (t < NBL) ? partials[t] : 0;
    sh[t] = v;
    __syncthreads();
    for (int d = 1; d < 256; d <<= 1) {
        int u = (t >= d) ? sh[t - d] : 0;
        __syncthreads();
        sh[t] += u;
        __syncthreads();
    }
    if (t < NBL) pscan[t] = sh[t] - v;
    if (t == 255) off[NN] = sh[255];
}

__global__ __launch_bounds__(256) void offs_k(const int* __restrict__ cnt,
                                              const int* __restrict__ pscan,
                                              int* __restrict__ off,
                                              int* __restrict__ cur) {
    __shared__ int sh[256];
    int t = threadIdx.x;
    int idx = blockIdx.x * 256 + t;
    int v = (idx < NN) ? cnt[idx] : 0;
    sh[t] = v;
    __syncthreads();
    for (int d = 1; d < 256; d <<= 1) {
        int u = (t >= d) ? sh[t - d] : 0;
        __syncthreads();
        sh[t] += u;
        __syncthreads();
    }
    if (idx < NN) {
        int o = pscan[blockIdx.x] + sh[t] - v;
        off[idx] = o;
        cur[idx] = o;
    }
}

__global__ void fill_k(const int* __restrict__ src, const int* __restrict__ dst,
                       const float* __restrict__ attr, int* __restrict__ cur,
                       int2* __restrict__ cedge) {
    int e = blockIdx.x * blockDim.x + threadIdx.x;
    if (e < NE) {
        int d = dst[e];
        int p = atomicAdd(&cur[d], 1);
        cedge[p] = make_int2(src[e], __float_as_int(attr[e]));
    }
}

// ---------------- weight prep: swizzle into MFMA B-fragment order, bf16 ----------------
// conv mats: prep[((t*2+s)*64+l)*8+j] = W[k=32s+8*(l>>4)+j][n=16t+(l&15)]
// lin  mat : prep[24576 + ((t*4+s)*64+l)*8+j], k in [0,128)

__global__ __launch_bounds__(256) void wprep_k(const float* __restrict__ W1,
                                               const float* __restrict__ W2,
                                               const float* __restrict__ linW,
                                               short* __restrict__ prep) {
    int i = blockIdx.x * 256 + threadIdx.x;
    if (i < 24576) {
        int mat = i >> 12;   // layer*2 + (0:W1, 1:W2)
        int o = i & 4095;
        int j = o & 7, l = (o >> 3) & 63, s = (o >> 9) & 1, t = o >> 10;
        int k = 32 * s + 8 * (l >> 4) + j;
        int n = 16 * t + (l & 15);
        const float* Wsrc = (mat & 1) ? W2 : W1;
        prep[i] = (short)bfr(Wsrc[(mat >> 1) * 4096 + k * 64 + n]);
    } else if (i < 32768) {
        int o = i - 24576;
        int j = o & 7, l = (o >> 3) & 63, s = (o >> 9) & 3, t = o >> 11;
        int k = 32 * s + 8 * (l >> 4) + j;
        int n = 16 * t + (l & 15);
        prep[i] = (short)bfr(linW[k * 64 + n]);
    }
}

// ---------------- scatter: mb[n] = bf16( sum attr[e] * hb[src[e]] ) ----------------

__global__ __launch_bounds__(256) void scatter_k(const unsigned int* __restrict__ hb32,
                                                 const int* __restrict__ off,
                                                 const int2* __restrict__ cedge,
                                                 unsigned int* __restrict__ mb) {
    int w    = (blockIdx.x * blockDim.x + threadIdx.x) >> 6;
    int lane = threadIdx.x & 63;
    if (w >= NN) return;
    int half = lane >> 5;
    int u    = lane & 31;
    int s = off[w], e = off[w + 1];
    float acc0 = 0.f, acc1 = 0.f;
    int i = s;
    for (; i + 4 <= e; i += 4) {
        int2 eA = cedge[i + half];
        int2 eB = cedge[i + 2 + half];
        unsigned int hA = hb32[(size_t)eA.x * 32 + u];
        unsigned int hB = hb32[(size_t)eB.x * 32 + u];
        float aA = __int_as_float(eA.y);
        float aB = __int_as_float(eB.y);
        acc0 += aA * __uint_as_float(hA << 16);
        acc1 += aA * __uint_as_float(hA & 0xffff0000u);
        acc0 += aB * __uint_as_float(hB << 16);
        acc1 += aB * __uint_as_float(hB & 0xffff0000u);
    }
    for (; i + 2 <= e; i += 2) {
        int2 ed = cedge[i + half];
        unsigned int hv = hb32[(size_t)ed.x * 32 + u];
        float a = __int_as_float(ed.y);
        acc0 += a * __uint_as_float(hv << 16);
        acc1 += a * __uint_as_float(hv & 0xffff0000u);
    }
    if (i < e && half == 0) {
        int2 ed = cedge[i];
        unsigned int hv = hb32[(size_t)ed.x * 32 + u];
        float a = __int_as_float(ed.y);
        acc0 += a * __uint_as_float(hv << 16);
        acc1 += a * __uint_as_float(hv & 0xffff0000u);
    }
    acc0 += __shfl_xor(acc0, 32);
    acc1 += __shfl_xor(acc1, 32);
    if (half == 0)
        mb[(size_t)w * 32 + u] = bf2(acc0, acc1);
}

// ---------------- MFMA conv: out = [hprev +] relu(m@W1+b1)@W2+b2 ----------------
// 4 waves/block, wave = 16 rows. A-frags from bf16 m; B-frags pre-swizzled.
// stage1->stage2 transpose via per-wave LDS tile (pitch 72 shorts = 144B).

template <bool ADD, bool WB>
__global__ __launch_bounds__(256) void convm_k(const unsigned int* __restrict__ mb,
                                               const short* __restrict__ w1p,
                                               const float* __restrict__ b1,
                                               const short* __restrict__ w2p,
                                               const float* __restrict__ b2,
                                               const float* __restrict__ hprev,
                                               float* __restrict__ out,
                                               unsigned int* __restrict__ hb) {
    __shared__ short tls[4][16 * 72];
    int wv = threadIdx.x >> 6, l = threadIdx.x & 63;
    int c = l & 15, q = l >> 4;
    int rbase = blockIdx.x * 64 + wv * 16;

    // stage-1 A fragments: row = rbase+c, k = 32s+8q+j
    int ar = rbase + c;
    bool aok = ar < NN;
    uint4 v0 = make_uint4(0, 0, 0, 0), v1 = v0;
    if (aok) {
        const uint4* mp = (const uint4*)(mb + (size_t)ar * 32);
        v0 = mp[q];
        v1 = mp[4 + q];
    }
    bf16x8 a0 = *(bf16x8*)&v0, a1 = *(bf16x8*)&v1;

    const bf16x8* w1f = (const bf16x8*)w1p;
    const bf16x8* w2f = (const bf16x8*)w2p;

    f32x4 acc[4];
#pragma unroll
    for (int t = 0; t < 4; t++) acc[t] = (f32x4){0.f, 0.f, 0.f, 0.f};
#pragma unroll
    for (int t = 0; t < 4; t++) {
        acc[t] = MFMA(a0, w1f[(t * 2 + 0) * 64 + l], acc[t]);
        acc[t] = MFMA(a1, w1f[(t * 2 + 1) * 64 + l], acc[t]);
    }

    // bias + relu + bf16, transpose through LDS (C: col=c, row=4q+reg)
    short* tw = tls[wv];
#pragma unroll
    for (int t = 0; t < 4; t++) {
        float bb = b1[16 * t + c];
#pragma unroll
        for (int rg = 0; rg < 4; rg++) {
            float v = fmaxf(acc[t][rg] + bb, 0.f);
            tw[(4 * q + rg) * 72 + 16 * t + c] = (short)bfr(v);
        }
    }
    __syncthreads();

    // stage-2 A fragments: row-in-tile = c, k = 32s+8q+j
    bf16x8 ta0 = *(const bf16x8*)&tw[c * 72 + 8 * q];
    bf16x8 ta1 = *(const bf16x8*)&tw[c * 72 + 32 + 8 * q];

    f32x4 oc[4];
#pragma unroll
    for (int t = 0; t < 4; t++) oc[t] = (f32x4){0.f, 0.f, 0.f, 0.f};
#pragma unroll
    for (int t = 0; t < 4; t++) {
        oc[t] = MFMA(ta0, w2f[(t * 2 + 0) * 64 + l], oc[t]);
        oc[t] = MFMA(ta1, w2f[(t * 2 + 1) * 64 + l], oc[t]);
    }

#pragma unroll
    for (int t = 0; t < 4; t++) {
        float bb = b2[16 * t + c];
#pragma unroll
        for (int rg = 0; rg < 4; rg++) {
            int row = rbase + 4 * q + rg;
            if (row < NN) {
                float v = oc[t][rg] + bb;
                if constexpr (ADD) v += hprev[(size_t)row * 64 + 16 * t + c];
                out[(size_t)row * 64 + 16 * t + c] = v;
                if constexpr (WB) {
                    float o = __shfl_xor(v, 1);
                    if ((c & 1) == 0)
                        hb[(size_t)row * 32 + 8 * t + (c >> 1)] = bf2(v, o);
                }
            }
        }
    }
}

// ---------------- MFMA input linear: h0 = x @ lin_W + lin_b (+ bf16 copy) ----------------

__global__ __launch_bounds__(256) void linm_k(const float* __restrict__ x,
                                              const short* __restrict__ wp,
                                              const float* __restrict__ b,
                                              float* __restrict__ h0,
                                              unsigned int* __restrict__ hb) {
    int wv = threadIdx.x >> 6, l = threadIdx.x & 63;
    int c = l & 15, q = l >> 4;
    int rbase = blockIdx.x * 64 + wv * 16;
    int ar = rbase + c;
    bool aok = ar < NN;

    bf16x8 af[4];
#pragma unroll
    for (int s = 0; s < 4; s++) {
        float4 p0 = make_float4(0, 0, 0, 0), p1 = p0;
        if (aok) {
            const float4* xp = (const float4*)(x + (size_t)ar * FIN + 32 * s + 8 * q);
            p0 = xp[0];
            p1 = xp[1];
        }
        bf16x8 t;
        t[0] = (short)bfr(p0.x); t[1] = (short)bfr(p0.y);
        t[2] = (short)bfr(p0.z); t[3] = (short)bfr(p0.w);
        t[4] = (short)bfr(p1.x); t[5] = (short)bfr(p1.y);
        t[6] = (short)bfr(p1.z); t[7] = (short)bfr(p1.w);
        af[s] = t;
    }

    const bf16x8* wf = (const bf16x8*)wp;
    f32x4 acc[4];
#pragma unroll
    for (int t = 0; t < 4; t++) acc[t] = (f32x4){0.f, 0.f, 0.f, 0.f};
#pragma unroll
    for (int t = 0; t < 4; t++)
#pragma unroll
        for (int s = 0; s < 4; s++)
            acc[t] = MFMA(af[s], wf[(t * 4 + s) * 64 + l], acc[t]);

#pragma unroll
    for (int t = 0; t < 4; t++) {
        float bb = b[16 * t + c];
#pragma unroll
        for (int rg = 0; rg < 4; rg++) {
            int row = rbase + 4 * q + rg;
            if (row < NN) {
                float v = acc[t][rg] + bb;
                h0[(size_t)row * 64 + 16 * t + c] = v;
                float o = __shfl_xor(v, 1);
                if ((c & 1) == 0)
                    hb[(size_t)row * 32 + 8 * t + (c >> 1)] = bf2(v, o);
            }
        }
    }
}

// ---------------- launch ----------------

extern "C" void kernel_launch(void* const* d_in, const int* in_sizes, int n_in,
                              void* d_out, int out_size, void* d_ws, size_t ws_size,
                              hipStream_t stream) {
    (void)in_sizes; (void)n_in; (void)out_size; (void)ws_size;

    const float* x    = (const float*)d_in[0];
    const int*   ei   = (const int*)d_in[1];
    const float* attr = (const float*)d_in[2];
    const float* linW = (const float*)d_in[3];
    const float* linb = (const float*)d_in[4];
    const float* W1   = (const float*)d_in[5];
    const float* b1   = (const float*)d_in[6];
    const float* W2   = (const float*)d_in[7];
    const float* b2   = (const float*)d_in[8];
    float* out = (float*)d_out;

    // workspace (16B alignment at each boundary)
    float*        h0    = (float*)d_ws;                          // NN*64 f32
    unsigned int* mb    = (unsigned int*)(h0 + (size_t)NN * HD); // NN*32 (bf16 m)
    unsigned int* hb    = mb + (size_t)NN * 32;                  // NN*32 (bf16 h)
    int2*         cedge = (int2*)(hb + (size_t)NN * 32);         // NE
    short*        prep  = (short*)(cedge + NE);                  // 32768 shorts
    int*          cnt   = (int*)(prep + 32768);                  // NN
    int*          off   = cnt + NN;                              // NN+1
    int*          cur   = off + NN + 1;                          // NN
    int*          parts = cur + NN;                              // 256
    int*          pscan = parts + 256;                           // 256

    const int* src = ei;
    const int* dst = ei + NE;

    float* scats = out;
    float* outs  = out + (size_t)SL * NN * HD;

    const size_t NH = (size_t)NN * HD;
    const int EB = (NE + 255) / 256;
    const int WB_ = (NN * 64) / 256;

    const short* w1p0 = prep;            // layer i: prep + i*8192
    const short* w2p0 = prep + 4096;     // layer i: prep + i*8192 + 4096
    const short* linp = prep + 24576;

    // CSR build + weight prep
    hipMemsetAsync(cnt, 0, NN * sizeof(int), stream);
    hist_k<<<EB, 256, 0, stream>>>(dst, cnt);
    partial_k<<<NBL, 256, 0, stream>>>(cnt, parts);
    scanp_k<<<1, 256, 0, stream>>>(parts, pscan, off);
    offs_k<<<NBL, 256, 0, stream>>>(cnt, pscan, off, cur);
    fill_k<<<EB, 256, 0, stream>>>(src, dst, attr, cur, cedge);
    wprep_k<<<128, 256, 0, stream>>>(W1, W2, linW, prep);

    // h0 = x @ lin_W + lin_b (+ bf16 into hb)
    linm_k<<<GBM, 256, 0, stream>>>(x, linp, linb, h0, hb);

    // layer 0
    scatter_k<<<WB_, 256, 0, stream>>>(hb, off, cedge, mb);
    convm_k<true, true><<<GBM, 256, 0, stream>>>(mb, w1p0, b1, w2p0, b2, h0, outs, hb);

    // scatter(outs0): scats0 (W0) + layer-1 conv (W1)
    scatter_k<<<WB_, 256, 0, stream>>>(hb, off, cedge, mb);
    convm_k<false, false><<<GBM, 256, 0, stream>>>(mb, w1p0, b1, w2p0, b2, nullptr, scats, nullptr);
    convm_k<true, true><<<GBM, 256, 0, stream>>>(mb, w1p0 + 8192, b1 + 64, w2p0 + 8192, b2 + 64,
                                                 outs, outs + NH, hb);

    // scatter(outs1): scats1 (W1) + layer-2 conv (W2)
    scatter_k<<<WB_, 256, 0, stream>>>(hb, off, cedge, mb);
    convm_k<false, false><<<GBM, 256, 0, stream>>>(mb, w1p0 + 8192, b1 + 64, w2p0 + 8192, b2 + 64,
                                                   nullptr, scats + NH, nullptr);
    convm_k<true, true><<<GBM, 256, 0, stream>>>(mb, w1p0 + 16384, b1 + 128, w2p0 + 16384, b2 + 128,
                                                 outs + NH, outs + 2 * NH, hb);

    // scatter(outs2): scats2 (W2)
    scatter_k<<<WB_, 256, 0, stream>>>(hb, off, cedge, mb);
    convm_k<false, false><<<GBM, 256, 0, stream>>>(mb, w1p0 + 16384, b1 + 128, w2p0 + 16384, b2 + 128,
                                                   nullptr, scats + 2 * NH, nullptr);
}

// Round 5
// 273.179 us; speedup vs baseline: 1.8938x; 1.1269x over previous
//
#include <hip/hip_runtime.h>

#define NN 50000
#define NE 800000
#define FIN 128
#define HD 64
#define SL 3
#define NBL 196   // ceil(NN/256)
#define GBM 782   // ceil(NN/64) row-tiles for MFMA kernels

typedef __attribute__((ext_vector_type(8))) short bf16x8;
typedef __attribute__((ext_vector_type(4))) float f32x4;
#define MFMA(A, B, C) __builtin_amdgcn_mfma_f32_16x16x32_bf16(A, B, C, 0, 0, 0)

// ---------------- bf16 pack helpers (RNE) ----------------

__device__ __forceinline__ unsigned int bfr(float x) {
    unsigned int u = __float_as_uint(x);
    return (u + 0x7fffu + ((u >> 16) & 1u)) >> 16;
}
__device__ __forceinline__ unsigned int bf2(float lo, float hi) {
    return bfr(lo) | (bfr(hi) << 16);
}

// ---------------- CSR build ----------------

__global__ void hist_k(const int* __restrict__ dst, int* __restrict__ cnt) {
    int e = blockIdx.x * blockDim.x + threadIdx.x;
    if (e < NE) atomicAdd(&cnt[dst[e]], 1);
}

__global__ __launch_bounds__(256) void partial_k(const int* __restrict__ cnt,
                                                 int* __restrict__ partials) {
    __shared__ int sh[256];
    int t = threadIdx.x;
    int idx = blockIdx.x * 256 + t;
    sh[t] = (idx < NN) ? cnt[idx] : 0;
    __syncthreads();
    for (int d = 128; d > 0; d >>= 1) {
        if (t < d) sh[t] += sh[t + d];
        __syncthreads();
    }
    if (t == 0) partials[blockIdx.x] = sh[0];
}

__global__ __launch_bounds__(256) void scanp_k(const int* __restrict__ partials,
                                               int* __restrict__ pscan,
                                               int* __restrict__ off) {
    __shared__ int sh[256];
    int t = threadIdx.x;
    int v = (t < NBL) ? partials[t] : 0;
    sh[t] = v;
    __syncthreads();
    for (int d = 1; d < 256; d <<= 1) {
        int u = (t >= d) ? sh[t - d] : 0;
        __syncthreads();
        sh[t] += u;
        __syncthreads();
    }
    if (t < NBL) pscan[t] = sh[t] - v;
    if (t == 255) off[NN] = sh[255];
}

__global__ __launch_bounds__(256) void offs_k(const int* __restrict__ cnt,
                                              const int* __restrict__ pscan,
                                              int* __restrict__ off,
                                              int* __restrict__ cur) {
    __shared__ int sh[256];
    int t = threadIdx.x;
    int idx = blockIdx.x * 256 + t;
    int v = (idx < NN) ? cnt[idx] : 0;
    sh[t] = v;
    __syncthreads();
    for (int d = 1; d < 256; d <<= 1) {
        int u = (t >= d) ? sh[t - d] : 0;
        __syncthreads();
        sh[t] += u;
        __syncthreads();
    }
    if (idx < NN) {
        int o = pscan[blockIdx.x] + sh[t] - v;
        off[idx] = o;
        cur[idx] = o;
    }
}

__global__ void fill_k(const int* __restrict__ src, const int* __restrict__ dst,
                       const float* __restrict__ attr, int* __restrict__ cur,
                       int2* __restrict__ cedge) {
    int e = blockIdx.x * blockDim.x + threadIdx.x;
    if (e < NE) {
        int d = dst[e];
        int p = atomicAdd(&cur[d], 1);
        cedge[p] = make_int2(src[e], __float_as_int(attr[e]));
    }
}

// ---------------- weight prep: swizzle into MFMA B-fragment order, bf16 ----------------

__global__ __launch_bounds__(256) void wprep_k(const float* __restrict__ W1,
                                               const float* __restrict__ W2,
                                               const float* __restrict__ linW,
                                               short* __restrict__ prep) {
    int i = blockIdx.x * 256 + threadIdx.x;
    if (i < 24576) {
        int mat = i >> 12;   // layer*2 + (0:W1, 1:W2)
        int o = i & 4095;
        int j = o & 7, l = (o >> 3) & 63, s = (o >> 9) & 1, t = o >> 10;
        int k = 32 * s + 8 * (l >> 4) + j;
        int n = 16 * t + (l & 15);
        const float* Wsrc = (mat & 1) ? W2 : W1;
        prep[i] = (short)bfr(Wsrc[(mat >> 1) * 4096 + k * 64 + n]);
    } else if (i < 32768) {
        int o = i - 24576;
        int j = o & 7, l = (o >> 3) & 63, s = (o >> 9) & 3, t = o >> 11;
        int k = 32 * s + 8 * (l >> 4) + j;
        int n = 16 * t + (l & 15);
        prep[i] = (short)bfr(linW[k * 64 + n]);
    }
}

// ---------------- scatter: mb[n] = bf16( sum attr[e] * hb[src[e]] ) ----------------
// wave per dst node; 8 edges per iteration. lane = (edge-slot g = l>>3,
// feature-chunk f = l&7). Each lane gathers uint4 (8 bf16 feats); per-group
// 8 lanes cover the full 128B row. Tree-reduce across edge slots at the end.

__global__ __launch_bounds__(256) void scatter_k(const uint4* __restrict__ hb4,
                                                 const int* __restrict__ off,
                                                 const int2* __restrict__ cedge,
                                                 uint4* __restrict__ mb4) {
    int w    = (blockIdx.x * blockDim.x + threadIdx.x) >> 6;
    int lane = threadIdx.x & 63;
    if (w >= NN) return;
    int g = lane >> 3;   // edge slot 0..7
    int f = lane & 7;    // uint4 chunk within row
    int s = off[w], e = off[w + 1];
    float acc0 = 0.f, acc1 = 0.f, acc2 = 0.f, acc3 = 0.f;
    float acc4 = 0.f, acc5 = 0.f, acc6 = 0.f, acc7 = 0.f;
    for (int i = s; i < e; i += 8) {
        int ei = i + g;
        if (ei < e) {
            int2 ed = cedge[ei];
            uint4 hv = hb4[(size_t)ed.x * 8 + f];
            float a = __int_as_float(ed.y);
            acc0 += a * __uint_as_float(hv.x << 16);
            acc1 += a * __uint_as_float(hv.x & 0xffff0000u);
            acc2 += a * __uint_as_float(hv.y << 16);
            acc3 += a * __uint_as_float(hv.y & 0xffff0000u);
            acc4 += a * __uint_as_float(hv.z << 16);
            acc5 += a * __uint_as_float(hv.z & 0xffff0000u);
            acc6 += a * __uint_as_float(hv.w << 16);
            acc7 += a * __uint_as_float(hv.w & 0xffff0000u);
        }
    }
#pragma unroll
    for (int msk = 8; msk <= 32; msk <<= 1) {
        acc0 += __shfl_xor(acc0, msk);
        acc1 += __shfl_xor(acc1, msk);
        acc2 += __shfl_xor(acc2, msk);
        acc3 += __shfl_xor(acc3, msk);
        acc4 += __shfl_xor(acc4, msk);
        acc5 += __shfl_xor(acc5, msk);
        acc6 += __shfl_xor(acc6, msk);
        acc7 += __shfl_xor(acc7, msk);
    }
    if (g == 0) {
        uint4 o;
        o.x = bf2(acc0, acc1);
        o.y = bf2(acc2, acc3);
        o.z = bf2(acc4, acc5);
        o.w = bf2(acc6, acc7);
        mb4[(size_t)w * 8 + f] = o;
    }
}

// ---------------- MFMA conv: out = [hprev +] relu(m@W1+b1)@W2+b2 ----------------

template <bool ADD, bool WB>
__global__ __launch_bounds__(256) void convm_k(const unsigned int* __restrict__ mb,
                                               const short* __restrict__ w1p,
                                               const float* __restrict__ b1,
                                               const short* __restrict__ w2p,
                                               const float* __restrict__ b2,
                                               const float* __restrict__ hprev,
                                               float* __restrict__ out,
                                               unsigned int* __restrict__ hb) {
    __shared__ short tls[4][16 * 72];
    int wv = threadIdx.x >> 6, l = threadIdx.x & 63;
    int c = l & 15, q = l >> 4;
    int rbase = blockIdx.x * 64 + wv * 16;

    int ar = rbase + c;
    bool aok = ar < NN;
    uint4 v0 = make_uint4(0, 0, 0, 0), v1 = v0;
    if (aok) {
        const uint4* mp = (const uint4*)(mb + (size_t)ar * 32);
        v0 = mp[q];
        v1 = mp[4 + q];
    }
    bf16x8 a0 = *(bf16x8*)&v0, a1 = *(bf16x8*)&v1;

    const bf16x8* w1f = (const bf16x8*)w1p;
    const bf16x8* w2f = (const bf16x8*)w2p;

    f32x4 acc[4];
#pragma unroll
    for (int t = 0; t < 4; t++) acc[t] = (f32x4){0.f, 0.f, 0.f, 0.f};
#pragma unroll
    for (int t = 0; t < 4; t++) {
        acc[t] = MFMA(a0, w1f[(t * 2 + 0) * 64 + l], acc[t]);
        acc[t] = MFMA(a1, w1f[(t * 2 + 1) * 64 + l], acc[t]);
    }

    short* tw = tls[wv];
#pragma unroll
    for (int t = 0; t < 4; t++) {
        float bb = b1[16 * t + c];
#pragma unroll
        for (int rg = 0; rg < 4; rg++) {
            float v = fmaxf(acc[t][rg] + bb, 0.f);
            tw[(4 * q + rg) * 72 + 16 * t + c] = (short)bfr(v);
        }
    }
    __syncthreads();

    bf16x8 ta0 = *(const bf16x8*)&tw[c * 72 + 8 * q];
    bf16x8 ta1 = *(const bf16x8*)&tw[c * 72 + 32 + 8 * q];

    f32x4 oc[4];
#pragma unroll
    for (int t = 0; t < 4; t++) oc[t] = (f32x4){0.f, 0.f, 0.f, 0.f};
#pragma unroll
    for (int t = 0; t < 4; t++) {
        oc[t] = MFMA(ta0, w2f[(t * 2 + 0) * 64 + l], oc[t]);
        oc[t] = MFMA(ta1, w2f[(t * 2 + 1) * 64 + l], oc[t]);
    }

#pragma unroll
    for (int t = 0; t < 4; t++) {
        float bb = b2[16 * t + c];
#pragma unroll
        for (int rg = 0; rg < 4; rg++) {
            int row = rbase + 4 * q + rg;
            if (row < NN) {
                float v = oc[t][rg] + bb;
                if constexpr (ADD) v += hprev[(size_t)row * 64 + 16 * t + c];
                out[(size_t)row * 64 + 16 * t + c] = v;
                if constexpr (WB) {
                    float o = __shfl_xor(v, 1);
                    if ((c & 1) == 0)
                        hb[(size_t)row * 32 + 8 * t + (c >> 1)] = bf2(v, o);
                }
            }
        }
    }
}

// ---------------- MFMA input linear: h0 = x @ lin_W + lin_b (+ bf16 copy) ----------------

__global__ __launch_bounds__(256) void linm_k(const float* __restrict__ x,
                                              const short* __restrict__ wp,
                                              const float* __restrict__ b,
                                              float* __restrict__ h0,
                                              unsigned int* __restrict__ hb) {
    int wv = threadIdx.x >> 6, l = threadIdx.x & 63;
    int c = l & 15, q = l >> 4;
    int rbase = blockIdx.x * 64 + wv * 16;
    int ar = rbase + c;
    bool aok = ar < NN;

    bf16x8 af[4];
#pragma unroll
    for (int s = 0; s < 4; s++) {
        float4 p0 = make_float4(0, 0, 0, 0), p1 = p0;
        if (aok) {
            const float4* xp = (const float4*)(x + (size_t)ar * FIN + 32 * s + 8 * q);
            p0 = xp[0];
            p1 = xp[1];
        }
        bf16x8 t;
        t[0] = (short)bfr(p0.x); t[1] = (short)bfr(p0.y);
        t[2] = (short)bfr(p0.z); t[3] = (short)bfr(p0.w);
        t[4] = (short)bfr(p1.x); t[5] = (short)bfr(p1.y);
        t[6] = (short)bfr(p1.z); t[7] = (short)bfr(p1.w);
        af[s] = t;
    }

    const bf16x8* wf = (const bf16x8*)wp;
    f32x4 acc[4];
#pragma unroll
    for (int t = 0; t < 4; t++) acc[t] = (f32x4){0.f, 0.f, 0.f, 0.f};
#pragma unroll
    for (int t = 0; t < 4; t++)
#pragma unroll
        for (int s = 0; s < 4; s++)
            acc[t] = MFMA(af[s], wf[(t * 4 + s) * 64 + l], acc[t]);

#pragma unroll
    for (int t = 0; t < 4; t++) {
        float bb = b[16 * t + c];
#pragma unroll
        for (int rg = 0; rg < 4; rg++) {
            int row = rbase + 4 * q + rg;
            if (row < NN) {
                float v = acc[t][rg] + bb;
                h0[(size_t)row * 64 + 16 * t + c] = v;
                float o = __shfl_xor(v, 1);
                if ((c & 1) == 0)
                    hb[(size_t)row * 32 + 8 * t + (c >> 1)] = bf2(v, o);
            }
        }
    }
}

// ---------------- launch ----------------

extern "C" void kernel_launch(void* const* d_in, const int* in_sizes, int n_in,
                              void* d_out, int out_size, void* d_ws, size_t ws_size,
                              hipStream_t stream) {
    (void)in_sizes; (void)n_in; (void)out_size; (void)ws_size;

    const float* x    = (const float*)d_in[0];
    const int*   ei   = (const int*)d_in[1];
    const float* attr = (const float*)d_in[2];
    const float* linW = (const float*)d_in[3];
    const float* linb = (const float*)d_in[4];
    const float* W1   = (const float*)d_in[5];
    const float* b1   = (const float*)d_in[6];
    const float* W2   = (const float*)d_in[7];
    const float* b2   = (const float*)d_in[8];
    float* out = (float*)d_out;

    // workspace (16B alignment at each boundary)
    float*        h0    = (float*)d_ws;                          // NN*64 f32
    unsigned int* mb    = (unsigned int*)(h0 + (size_t)NN * HD); // NN*32 (bf16 m)
    unsigned int* hb    = mb + (size_t)NN * 32;                  // NN*32 (bf16 h)
    int2*         cedge = (int2*)(hb + (size_t)NN * 32);         // NE
    short*        prep  = (short*)(cedge + NE);                  // 32768 shorts
    int*          cnt   = (int*)(prep + 32768);                  // NN
    int*          off   = cnt + NN;                              // NN+1
    int*          cur   = off + NN + 1;                          // NN
    int*          parts = cur + NN;                              // 256
    int*          pscan = parts + 256;                           // 256

    const int* src = ei;
    const int* dst = ei + NE;

    float* scats = out;
    float* outs  = out + (size_t)SL * NN * HD;

    const size_t NH = (size_t)NN * HD;
    const int EB = (NE + 255) / 256;
    const int WB_ = (NN * 64) / 256;

    const short* w1p0 = prep;            // layer i: prep + i*8192
    const short* w2p0 = prep + 4096;     // layer i: prep + i*8192 + 4096
    const short* linp = prep + 24576;

    // CSR build + weight prep
    hipMemsetAsync(cnt, 0, NN * sizeof(int), stream);
    hist_k<<<EB, 256, 0, stream>>>(dst, cnt);
    partial_k<<<NBL, 256, 0, stream>>>(cnt, parts);
    scanp_k<<<1, 256, 0, stream>>>(parts, pscan, off);
    offs_k<<<NBL, 256, 0, stream>>>(cnt, pscan, off, cur);
    fill_k<<<EB, 256, 0, stream>>>(src, dst, attr, cur, cedge);
    wprep_k<<<128, 256, 0, stream>>>(W1, W2, linW, prep);

    // h0 = x @ lin_W + lin_b (+ bf16 into hb)
    linm_k<<<GBM, 256, 0, stream>>>(x, linp, linb, h0, hb);

    // layer 0
    scatter_k<<<WB_, 256, 0, stream>>>((const uint4*)hb, off, cedge, (uint4*)mb);
    convm_k<true, true><<<GBM, 256, 0, stream>>>(mb, w1p0, b1, w2p0, b2, h0, outs, hb);

    // scatter(outs0): scats0 (W0) + layer-1 conv (W1)
    scatter_k<<<WB_, 256, 0, stream>>>((const uint4*)hb, off, cedge, (uint4*)mb);
    convm_k<false, false><<<GBM, 256, 0, stream>>>(mb, w1p0, b1, w2p0, b2, nullptr, scats, nullptr);
    convm_k<true, true><<<GBM, 256, 0, stream>>>(mb, w1p0 + 8192, b1 + 64, w2p0 + 8192, b2 + 64,
                                                 outs, outs + NH, hb);

    // scatter(outs1): scats1 (W1) + layer-2 conv (W2)
    scatter_k<<<WB_, 256, 0, stream>>>((const uint4*)hb, off, cedge, (uint4*)mb);
    convm_k<false, false><<<GBM, 256, 0, stream>>>(mb, w1p0 + 8192, b1 + 64, w2p0 + 8192, b2 + 64,
                                                   nullptr, scats + NH, nullptr);
    convm_k<true, true><<<GBM, 256, 0, stream>>>(mb, w1p0 + 16384, b1 + 128, w2p0 + 16384, b2 + 128,
                                                 outs + NH, outs + 2 * NH, hb);

    // scatter(outs2): scats2 (W2)
    scatter_k<<<WB_, 256, 0, stream>>>((const uint4*)hb, off, cedge, (uint4*)mb);
    convm_k<false, false><<<GBM, 256, 0, stream>>>(mb, w1p0 + 16384, b1 + 128, w2p0 + 16384, b2 + 128,
                                                   nullptr, scats + 2 * NH, nullptr);
}